// Round 3
// baseline (150.431 us; speedup 1.0000x reference)
//
#include <hip/hip_runtime.h>

typedef float v2f __attribute__((ext_vector_type(2)));

__device__ __forceinline__ float fexp2(float x) { return __builtin_amdgcn_exp2f(x); }
__device__ __forceinline__ float flog2(float x) { return __builtin_amdgcn_logf(x); }
__device__ __forceinline__ float frcp (float x) { return __builtin_amdgcn_rcpf(x); }
__device__ __forceinline__ float ffma (float a, float b, float c) { return __builtin_fmaf(a, b, c); }
__device__ __forceinline__ v2f  splat(float s) { v2f v; v.x = s; v.y = s; return v; }
__device__ __forceinline__ v2f  pkfma(v2f a, v2f b, v2f c) { return __builtin_elementwise_fma(a, b, c); }

#define LAB_EPS 0.008856f
#define F16_116 0.13793103448275862f   // 16/116

// ws layout (floats):
//   [0   .. 511]  per-j pairs: wa={w1_0j,w1_1j,w1_2j,b1_j} at 8j, wb={w2p_j0,w2p_j1,w2p_j2,0} at 8j+4
//   [512 .. 520]  A[9]      (x -> out direct path)
//   [521 .. 529]  U[9]      (fX,fY,fZ -> out folded path)
//   [530 .. 538]  Wld[9]    (w_logd)
//   [539 .. 541]  bld[3]
//   [542 .. 544]  cv[3]     (all biases folded, incl. -16*Wfb row)
__global__ __launch_bounds__(64) void fold_kernel(
    const float* __restrict__ w_seq1, const float* __restrict__ b_seq1,
    const float* __restrict__ w_seq2, const float* __restrict__ b_seq2,
    const float* __restrict__ w_lin,  const float* __restrict__ b_lin,
    const float* __restrict__ w_comb, const float* __restrict__ b_comb,
    const float* __restrict__ w_logd, const float* __restrict__ b_logd,
    const float* __restrict__ w_final,const float* __restrict__ b_final,
    float* __restrict__ ws)
{
    const int j = threadIdx.x;
    float H3[9];
    for (int i = 0; i < 3; ++i)
        for (int c = 0; c < 3; ++c) {
            float h = 0.f;
            for (int m = 0; m < 3; ++m) h += w_comb[(i + 3) * 3 + m] * w_final[m * 3 + c];
            H3[i * 3 + c] = h;
        }
    const float w0 = w_seq2[j * 3 + 0], w1 = w_seq2[j * 3 + 1], w2 = w_seq2[j * 3 + 2];
    float4* wf = reinterpret_cast<float4*>(ws);
    wf[2 * j]     = make_float4(w_seq1[j], w_seq1[64 + j], w_seq1[128 + j], b_seq1[j]);
    wf[2 * j + 1] = make_float4(w0 * H3[0] + w1 * H3[3] + w2 * H3[6],
                                w0 * H3[1] + w1 * H3[4] + w2 * H3[7],
                                w0 * H3[2] + w1 * H3[5] + w2 * H3[8], 0.f);
    if (j == 0) {
        float G[9], Wfb[9];
        for (int i = 0; i < 3; ++i)
            for (int c = 0; c < 3; ++c) {
                float gg = 0.f;
                for (int m = 0; m < 3; ++m) gg += w_comb[i * 3 + m] * w_final[m * 3 + c];
                G[i * 3 + c] = gg;
            }
        for (int k = 0; k < 3; ++k)
            for (int c = 0; c < 3; ++c) {
                float s = 0.f;
                for (int i = 0; i < 3; ++i) s += w_lin[k * 3 + i] * G[i * 3 + c];
                ws[512 + k * 3 + c] = s;                          // A
                Wfb[k * 3 + c]      = w_final[(k + 3) * 3 + c];
                ws[530 + k * 3 + c] = w_logd[k * 3 + c];          // Wld
            }
        for (int c = 0; c < 3; ++c) {
            // U: out += fX*U[c] + fY*U[3+c] + fZ*U[6+c]  (bL/bA/bB algebra folded)
            ws[521 + c]     = 500.0f * Wfb[3 + c];
            ws[521 + 3 + c] = 116.0f * Wfb[c] - 500.0f * Wfb[3 + c] + 200.0f * Wfb[6 + c];
            ws[521 + 6 + c] = -200.0f * Wfb[6 + c];
            float s = b_final[c] - 16.0f * Wfb[c];
            for (int i = 0; i < 3; ++i)
                s += b_lin[i] * G[i * 3 + c] + b_seq2[i] * H3[i * 3 + c]
                   + b_comb[i] * w_final[i * 3 + c];
            ws[539 + c] = b_logd[c];
            ws[542 + c] = s;                                      // cv
        }
    }
}

// P=4 points/thread, block=256 -> 2048 blocks. No LDS; weights via scalar loads.
__global__ __launch_bounds__(256) void fused_kernel(
    const float* __restrict__ x, const float* __restrict__ ws,
    float* __restrict__ out, int n)
{
    const int g = blockIdx.x * blockDim.x + threadIdx.x;
    if (g * 4 >= n) return;

    const float4* xin = reinterpret_cast<const float4*>(x) + (size_t)g * 3;
    const float4 v0 = xin[0], v1 = xin[1], v2 = xin[2];

    // xs2[q][c] = {pt(2q) ch c, pt(2q+1) ch c}
    v2f xs2[2][3];
    xs2[0][0].x = v0.x; xs2[0][0].y = v0.w;
    xs2[0][1].x = v0.y; xs2[0][1].y = v1.x;
    xs2[0][2].x = v0.z; xs2[0][2].y = v1.y;
    xs2[1][0].x = v1.z; xs2[1][0].y = v2.y;
    xs2[1][1].x = v1.w; xs2[1][1].y = v2.z;
    xs2[1][2].x = v2.x; xs2[1][2].y = v2.w;

    v2f acc2[2][3];
#pragma unroll
    for (int q = 0; q < 2; ++q)
#pragma unroll
        for (int c = 0; c < 3; ++c) acc2[q][c] = splat(0.f);

    const float4* wf = reinterpret_cast<const float4*>(ws);
    // Hidden layer: h = tanh(x.w1+b1) via Pade/continued-fraction (|err|<7e-4),
    // one v_rcp per PAIR (denominators >0, product < 4.3e12 -> no overflow).
#pragma unroll 4
    for (int j = 0; j < 64; ++j) {
        const float4 wa = wf[2 * j];       // uniform address -> s_load broadcast
        const float4 wb = wf[2 * j + 1];
#pragma unroll
        for (int q = 0; q < 2; ++q) {
            v2f t = pkfma(xs2[q][0], splat(wa.x),
                    pkfma(xs2[q][1], splat(wa.y),
                    pkfma(xs2[q][2], splat(wa.z), splat(wa.w))));
            t = __builtin_elementwise_min(__builtin_elementwise_max(t, splat(-4.0f)), splat(4.0f));
            const v2f u = t * t;
            v2f p = u + splat(378.0f);
            p = pkfma(p, u, splat(17325.0f));
            p = pkfma(p, u, splat(135135.0f));
            v2f qd = pkfma(splat(28.0f), u, splat(3150.0f));
            qd = pkfma(qd, u, splat(62370.0f));
            qd = pkfma(qd, u, splat(135135.0f));
            const v2f tp = t * p;
            const float ir = frcp(qd.x * qd.y);
            v2f iq; iq.x = ir * qd.y; iq.y = ir * qd.x;
            const v2f h = tp * iq;
            acc2[q][0] = pkfma(h, splat(wb.x), acc2[q][0]);
            acc2[q][1] = pkfma(h, splat(wb.y), acc2[q][1]);
            acc2[q][2] = pkfma(h, splat(wb.z), acc2[q][2]);
        }
    }

    // Epilogue constants (uniform -> SGPRs)
    float A[9], U[9], Wld[9], bld[3], cv[3];
#pragma unroll
    for (int i = 0; i < 9; ++i) { A[i] = ws[512 + i]; U[i] = ws[521 + i]; Wld[i] = ws[530 + i]; }
#pragma unroll
    for (int i = 0; i < 3; ++i) { bld[i] = ws[539 + i]; cv[i] = ws[542 + i]; }

    float ov[12];
#pragma unroll
    for (int p = 0; p < 4; ++p) {
        const int q = p >> 1, s = p & 1;
        const float L  = s ? xs2[q][0].y : xs2[q][0].x;
        const float aa = s ? xs2[q][1].y : xs2[q][1].x;
        const float bb = s ? xs2[q][2].y : xs2[q][2].x;
        const float a0 = s ? acc2[q][0].y : acc2[q][0].x;
        const float a1 = s ? acc2[q][1].y : acc2[q][1].x;
        const float a2 = s ? acc2[q][2].y : acc2[q][2].x;
        // ---- lab2rgb(x) ----
        const float fy = (L + 16.0f) * (1.0f / 116.0f);
        const float fx = ffma(aa,  0.002f, fy);
        const float fz = ffma(bb, -0.005f, fy);
        float rgb[3];
        {
            const float f3x = fx * fx * fx, f3y = fy * fy * fy, f3z = fz * fz * fz;
            const float tx = f3x > LAB_EPS ? f3x : (fx - F16_116) * (1.0f / 7.787f);
            const float ty = f3y > LAB_EPS ? f3y : (fy - F16_116) * (1.0f / 7.787f);
            const float tz = f3z > LAB_EPS ? f3z : (fz - F16_116) * (1.0f / 7.787f);
            const float X = tx * 0.95047f, Y = ty, Z = tz * 1.08883f;
            const float linv[3] = {
                 3.2404542f * X - 1.5371385f * Y - 0.4985314f * Z,
                -0.9692660f * X + 1.8760108f * Y + 0.0415560f * Z,
                 0.0556434f * X - 0.2040259f * Y + 1.0572252f * Z};
#pragma unroll
            for (int c = 0; c < 3; ++c) {
                const float cc = linv[c];
                const float lo = 12.92f * cc;
                const float hi = ffma(1.055f,
                                      fexp2(flog2(fmaxf(cc, 0.0031308f)) * (1.0f / 2.4f)),
                                      -0.055f);
                rgb[c] = cc <= 0.0031308f ? lo : hi;
            }
        }
        // ---- -log10 -> @Wld+bld -> 10^ -> srgb_to_linear ----
        const float ld0 = -0.30102999566398120f * flog2(rgb[0]);
        const float ld1 = -0.30102999566398120f * flog2(rgb[1]);
        const float ld2 = -0.30102999566398120f * flog2(rgb[2]);
        float lin2[3];
#pragma unroll
        for (int c = 0; c < 3; ++c) {
            const float mp  = ffma(ld0, Wld[c], ffma(ld1, Wld[3 + c], ffma(ld2, Wld[6 + c], bld[c])));
            const float r10 = fexp2(mp * 3.3219280948873623f);   // 10^mp
            const float lo  = r10 * (1.0f / 12.92f);
            const float base = (fmaxf(r10, 0.04045f) + 0.055f) * (1.0f / 1.055f);
            const float hi  = fexp2(2.4f * flog2(base));
            lin2[c] = r10 <= 0.04045f ? lo : hi;
        }
        // ---- rgb2lab ----
        const float X2 = (0.412453f * lin2[0] + 0.357580f * lin2[1] + 0.180423f * lin2[2]) * (1.0f / 0.95047f);
        const float Y2 =  0.212671f * lin2[0] + 0.715160f * lin2[1] + 0.072169f * lin2[2];
        const float Z2 = (0.019334f * lin2[0] + 0.119193f * lin2[1] + 0.950227f * lin2[2]) * (1.0f / 1.08883f);
        const float fX = X2 > LAB_EPS ? fexp2(flog2(fmaxf(X2, LAB_EPS)) * (1.0f / 3.0f)) : ffma(7.787f, X2, F16_116);
        const float fY = Y2 > LAB_EPS ? fexp2(flog2(fmaxf(Y2, LAB_EPS)) * (1.0f / 3.0f)) : ffma(7.787f, Y2, F16_116);
        const float fZ = Z2 > LAB_EPS ? fexp2(flog2(fmaxf(Z2, LAB_EPS)) * (1.0f / 3.0f)) : ffma(7.787f, Z2, F16_116);
        // ---- final combine (U-folded) ----
#pragma unroll
        for (int c = 0; c < 3; ++c) {
            float o = cv[c];
            o = ffma(L,  A[c],     o);
            o = ffma(aa, A[3 + c], o);
            o = ffma(bb, A[6 + c], o);
            o += (c == 0 ? a0 : (c == 1 ? a1 : a2));
            o = ffma(fX, U[c],     o);
            o = ffma(fY, U[3 + c], o);
            o = ffma(fZ, U[6 + c], o);
            ov[p * 3 + c] = o;
        }
    }

    float4* op = reinterpret_cast<float4*>(out) + (size_t)g * 3;
#pragma unroll
    for (int i = 0; i < 3; ++i)
        op[i] = make_float4(ov[4 * i], ov[4 * i + 1], ov[4 * i + 2], ov[4 * i + 3]);
}

extern "C" void kernel_launch(void* const* d_in, const int* in_sizes, int n_in,
                              void* d_out, int out_size, void* d_ws, size_t ws_size,
                              hipStream_t stream)
{
    const float* x       = (const float*)d_in[0];
    float* ws            = (float*)d_ws;
    float* outp          = (float*)d_out;

    fold_kernel<<<1, 64, 0, stream>>>(
        (const float*)d_in[1], (const float*)d_in[2], (const float*)d_in[3],
        (const float*)d_in[4], (const float*)d_in[5], (const float*)d_in[6],
        (const float*)d_in[7], (const float*)d_in[8], (const float*)d_in[9],
        (const float*)d_in[10], (const float*)d_in[11], (const float*)d_in[12], ws);

    const int n = in_sizes[0] / 3;            // 2,097,152 points
    const int threads = 256;
    const int total_threads = (n + 3) / 4;    // 4 points per thread
    const int blocks = (total_threads + threads - 1) / threads;

    fused_kernel<<<blocks, threads, 0, stream>>>(x, ws, outp, n);
}

// Round 4
// 148.203 us; speedup vs baseline: 1.0150x; 1.0150x over previous
//
#include <hip/hip_runtime.h>

typedef float v2f __attribute__((ext_vector_type(2)));

__device__ __forceinline__ float fexp2(float x) { return __builtin_amdgcn_exp2f(x); }
__device__ __forceinline__ float flog2(float x) { return __builtin_amdgcn_logf(x); }
__device__ __forceinline__ float frcp (float x) { return __builtin_amdgcn_rcpf(x); }
__device__ __forceinline__ float ffma (float a, float b, float c) { return __builtin_fmaf(a, b, c); }
__device__ __forceinline__ v2f  splat(float s) { v2f v; v.x = s; v.y = s; return v; }
__device__ __forceinline__ v2f  pkfma(v2f a, v2f b, v2f c) { return __builtin_elementwise_fma(a, b, c); }

#define LAB_EPS 0.008856f
#define F16_116 0.13793103448275862f   // 16/116

// P=4 points/thread, block=256 -> 2048 blocks (8 blocks/CU possible).
// Weights broadcast from LDS (validated fastest path, R1); tanh via [5/4] Pade
// with ONE v_rcp shared across all 4 points (validated rational family, R2).
// Folded algebra: out = x@A + h@W2p + {fX,fY,fZ}@U + cv
__global__ __launch_bounds__(256) void fused_kernel(
    const float* __restrict__ x,
    const float* __restrict__ w_seq1, const float* __restrict__ b_seq1,
    const float* __restrict__ w_seq2, const float* __restrict__ b_seq2,
    const float* __restrict__ w_lin,  const float* __restrict__ b_lin,
    const float* __restrict__ w_comb, const float* __restrict__ b_comb,
    const float* __restrict__ w_logd, const float* __restrict__ b_logd,
    const float* __restrict__ w_final,const float* __restrict__ b_final,
    float* __restrict__ out, int n)
{
    __shared__ float4 wlds[128];   // 2j: {w1_0j,w1_1j,w1_2j,b1_j}, 2j+1: {w2p_j0..2, 0}
    __shared__ float  smlds[33];   // A[9], U[9], Wld[9], bld[3], cv[3]

    const int tid = threadIdx.x;
    if (tid < 64) {
        const int j = tid;
        float H3[9];
        for (int i = 0; i < 3; ++i)
            for (int c = 0; c < 3; ++c) {
                float h = 0.f;
                for (int m = 0; m < 3; ++m) h += w_comb[(i + 3) * 3 + m] * w_final[m * 3 + c];
                H3[i * 3 + c] = h;
            }
        const float w0 = w_seq2[j * 3 + 0], w1 = w_seq2[j * 3 + 1], w2 = w_seq2[j * 3 + 2];
        wlds[2 * j]     = make_float4(w_seq1[j], w_seq1[64 + j], w_seq1[128 + j], b_seq1[j]);
        wlds[2 * j + 1] = make_float4(w0 * H3[0] + w1 * H3[3] + w2 * H3[6],
                                      w0 * H3[1] + w1 * H3[4] + w2 * H3[7],
                                      w0 * H3[2] + w1 * H3[5] + w2 * H3[8], 0.f);
        if (j == 0) {
            float G[9], Wfb[9];
            for (int i = 0; i < 3; ++i)
                for (int c = 0; c < 3; ++c) {
                    float gg = 0.f;
                    for (int m = 0; m < 3; ++m) gg += w_comb[i * 3 + m] * w_final[m * 3 + c];
                    G[i * 3 + c] = gg;
                }
            for (int k = 0; k < 3; ++k)
                for (int c = 0; c < 3; ++c) {
                    float s = 0.f;
                    for (int i = 0; i < 3; ++i) s += w_lin[k * 3 + i] * G[i * 3 + c];
                    smlds[k * 3 + c] = s;                         // A
                    Wfb[k * 3 + c]   = w_final[(k + 3) * 3 + c];
                    smlds[18 + k * 3 + c] = w_logd[k * 3 + c];    // Wld
                }
            for (int c = 0; c < 3; ++c) {
                smlds[9 + c]     = 500.0f * Wfb[3 + c];                                   // U row fX
                smlds[9 + 3 + c] = 116.0f * Wfb[c] - 500.0f * Wfb[3 + c] + 200.0f * Wfb[6 + c]; // fY
                smlds[9 + 6 + c] = -200.0f * Wfb[6 + c];                                  // fZ
                float s = b_final[c] - 16.0f * Wfb[c];
                for (int i = 0; i < 3; ++i)
                    s += b_lin[i] * G[i * 3 + c] + b_seq2[i] * H3[i * 3 + c]
                       + b_comb[i] * w_final[i * 3 + c];
                smlds[27 + c] = b_logd[c];
                smlds[30 + c] = s;                                // cv
            }
        }
    }
    __syncthreads();

    const int g = blockIdx.x * blockDim.x + tid;
    if (g * 4 >= n) return;

    const float4* xin = reinterpret_cast<const float4*>(x) + (size_t)g * 3;
    const float4 v0 = xin[0], v1 = xin[1], v2 = xin[2];

    v2f xs2[2][3];
    xs2[0][0].x = v0.x; xs2[0][0].y = v0.w;
    xs2[0][1].x = v0.y; xs2[0][1].y = v1.x;
    xs2[0][2].x = v0.z; xs2[0][2].y = v1.y;
    xs2[1][0].x = v1.z; xs2[1][0].y = v2.y;
    xs2[1][1].x = v1.w; xs2[1][1].y = v2.z;
    xs2[1][2].x = v2.x; xs2[1][2].y = v2.w;

    v2f acc2[2][3];
#pragma unroll
    for (int q = 0; q < 2; ++q)
#pragma unroll
        for (int c = 0; c < 3; ++c) acc2[q][c] = splat(0.f);

    // Hidden layer: h = tanh(t), t = x.w1+b1, via [5/4] Pade on clamped t:
    //   h = t(945+105u+u^2) / (945+420u+15u^2),  u = t^2, |t|<=4  (|err|<2.4e-3)
    // One v_rcp for all 4 points: den in [945,11505], prod4 <= 1.8e16 (safe).
#pragma unroll 4
    for (int j = 0; j < 64; ++j) {
        const float4 wa = wlds[2 * j];
        const float4 wb = wlds[2 * j + 1];
        v2f tp[2], qd[2];
#pragma unroll
        for (int q = 0; q < 2; ++q) {
            v2f t = pkfma(xs2[q][0], splat(wa.x),
                    pkfma(xs2[q][1], splat(wa.y),
                    pkfma(xs2[q][2], splat(wa.z), splat(wa.w))));
            t = __builtin_elementwise_min(__builtin_elementwise_max(t, splat(-4.0f)), splat(4.0f));
            const v2f u = t * t;
            v2f p = u + splat(105.0f);
            p = pkfma(p, u, splat(945.0f));
            v2f q2 = pkfma(splat(15.0f), u, splat(420.0f));
            qd[q] = pkfma(q2, u, splat(945.0f));
            tp[q] = t * p;
        }
        const float qab = qd[0].x * qd[0].y;
        const float qcd = qd[1].x * qd[1].y;
        const float ir  = frcp(qab * qcd);
        const float irab = ir * qcd, ircd = ir * qab;
        v2f iq0, iq1;
        iq0.x = irab * qd[0].y; iq0.y = irab * qd[0].x;
        iq1.x = ircd * qd[1].y; iq1.y = ircd * qd[1].x;
        const v2f h0 = tp[0] * iq0;
        const v2f h1 = tp[1] * iq1;
        acc2[0][0] = pkfma(h0, splat(wb.x), acc2[0][0]);
        acc2[0][1] = pkfma(h0, splat(wb.y), acc2[0][1]);
        acc2[0][2] = pkfma(h0, splat(wb.z), acc2[0][2]);
        acc2[1][0] = pkfma(h1, splat(wb.x), acc2[1][0]);
        acc2[1][1] = pkfma(h1, splat(wb.y), acc2[1][1]);
        acc2[1][2] = pkfma(h1, splat(wb.z), acc2[1][2]);
    }

    // Epilogue constants
    float A[9], U[9], Wld[9], bld[3], cv[3];
#pragma unroll
    for (int i = 0; i < 9; ++i) { A[i] = smlds[i]; U[i] = smlds[9 + i]; Wld[i] = smlds[18 + i]; }
#pragma unroll
    for (int i = 0; i < 3; ++i) { bld[i] = smlds[27 + i]; cv[i] = smlds[30 + i]; }

    float ov[12];
#pragma unroll
    for (int p = 0; p < 4; ++p) {
        const int q = p >> 1, s = p & 1;
        const float L  = s ? xs2[q][0].y : xs2[q][0].x;
        const float aa = s ? xs2[q][1].y : xs2[q][1].x;
        const float bb = s ? xs2[q][2].y : xs2[q][2].x;
        const float a0 = s ? acc2[q][0].y : acc2[q][0].x;
        const float a1 = s ? acc2[q][1].y : acc2[q][1].x;
        const float a2 = s ? acc2[q][2].y : acc2[q][2].x;
        // ---- lab2rgb(x) ----
        const float fy = (L + 16.0f) * (1.0f / 116.0f);
        const float fx = ffma(aa,  0.002f, fy);
        const float fz = ffma(bb, -0.005f, fy);
        float rgb[3];
        {
            const float f3x = fx * fx * fx, f3y = fy * fy * fy, f3z = fz * fz * fz;
            const float tx = f3x > LAB_EPS ? f3x : (fx - F16_116) * (1.0f / 7.787f);
            const float ty = f3y > LAB_EPS ? f3y : (fy - F16_116) * (1.0f / 7.787f);
            const float tz = f3z > LAB_EPS ? f3z : (fz - F16_116) * (1.0f / 7.787f);
            const float X = tx * 0.95047f, Y = ty, Z = tz * 1.08883f;
            const float linv[3] = {
                 3.2404542f * X - 1.5371385f * Y - 0.4985314f * Z,
                -0.9692660f * X + 1.8760108f * Y + 0.0415560f * Z,
                 0.0556434f * X - 0.2040259f * Y + 1.0572252f * Z};
#pragma unroll
            for (int c = 0; c < 3; ++c) {
                const float cc = linv[c];
                const float lo = 12.92f * cc;
                const float hi = ffma(1.055f,
                                      fexp2(flog2(fmaxf(cc, 0.0031308f)) * (1.0f / 2.4f)),
                                      -0.055f);
                rgb[c] = cc <= 0.0031308f ? lo : hi;
            }
        }
        // ---- -log10 -> @Wld+bld -> 10^ -> srgb_to_linear ----
        const float ld0 = -0.30102999566398120f * flog2(rgb[0]);
        const float ld1 = -0.30102999566398120f * flog2(rgb[1]);
        const float ld2 = -0.30102999566398120f * flog2(rgb[2]);
        float lin2[3];
#pragma unroll
        for (int c = 0; c < 3; ++c) {
            const float mp  = ffma(ld0, Wld[c], ffma(ld1, Wld[3 + c], ffma(ld2, Wld[6 + c], bld[c])));
            const float r10 = fexp2(mp * 3.3219280948873623f);   // 10^mp
            const float lo  = r10 * (1.0f / 12.92f);
            const float base = (fmaxf(r10, 0.04045f) + 0.055f) * (1.0f / 1.055f);
            const float hi  = fexp2(2.4f * flog2(base));
            lin2[c] = r10 <= 0.04045f ? lo : hi;
        }
        // ---- rgb2lab -> f-values ----
        const float X2 = (0.412453f * lin2[0] + 0.357580f * lin2[1] + 0.180423f * lin2[2]) * (1.0f / 0.95047f);
        const float Y2 =  0.212671f * lin2[0] + 0.715160f * lin2[1] + 0.072169f * lin2[2];
        const float Z2 = (0.019334f * lin2[0] + 0.119193f * lin2[1] + 0.950227f * lin2[2]) * (1.0f / 1.08883f);
        const float fX = X2 > LAB_EPS ? fexp2(flog2(fmaxf(X2, LAB_EPS)) * (1.0f / 3.0f)) : ffma(7.787f, X2, F16_116);
        const float fY = Y2 > LAB_EPS ? fexp2(flog2(fmaxf(Y2, LAB_EPS)) * (1.0f / 3.0f)) : ffma(7.787f, Y2, F16_116);
        const float fZ = Z2 > LAB_EPS ? fexp2(flog2(fmaxf(Z2, LAB_EPS)) * (1.0f / 3.0f)) : ffma(7.787f, Z2, F16_116);
        // ---- final combine (U-folded) ----
#pragma unroll
        for (int c = 0; c < 3; ++c) {
            float o = cv[c];
            o = ffma(L,  A[c],     o);
            o = ffma(aa, A[3 + c], o);
            o = ffma(bb, A[6 + c], o);
            o += (c == 0 ? a0 : (c == 1 ? a1 : a2));
            o = ffma(fX, U[c],     o);
            o = ffma(fY, U[3 + c], o);
            o = ffma(fZ, U[6 + c], o);
            ov[p * 3 + c] = o;
        }
    }

    float4* op = reinterpret_cast<float4*>(out) + (size_t)g * 3;
#pragma unroll
    for (int i = 0; i < 3; ++i)
        op[i] = make_float4(ov[4 * i], ov[4 * i + 1], ov[4 * i + 2], ov[4 * i + 3]);
}

extern "C" void kernel_launch(void* const* d_in, const int* in_sizes, int n_in,
                              void* d_out, int out_size, void* d_ws, size_t ws_size,
                              hipStream_t stream)
{
    const float* x       = (const float*)d_in[0];
    const float* w_seq1  = (const float*)d_in[1];
    const float* b_seq1  = (const float*)d_in[2];
    const float* w_seq2  = (const float*)d_in[3];
    const float* b_seq2  = (const float*)d_in[4];
    const float* w_lin   = (const float*)d_in[5];
    const float* b_lin   = (const float*)d_in[6];
    const float* w_comb  = (const float*)d_in[7];
    const float* b_comb  = (const float*)d_in[8];
    const float* w_logd  = (const float*)d_in[9];
    const float* b_logd  = (const float*)d_in[10];
    const float* w_final = (const float*)d_in[11];
    const float* b_final = (const float*)d_in[12];
    float* outp = (float*)d_out;

    const int n = in_sizes[0] / 3;            // 2,097,152 points
    const int threads = 256;
    const int total_threads = (n + 3) / 4;    // 4 points per thread
    const int blocks = (total_threads + threads - 1) / threads;

    fused_kernel<<<blocks, threads, 0, stream>>>(
        x, w_seq1, b_seq1, w_seq2, b_seq2, w_lin, b_lin, w_comb, b_comb,
        w_logd, b_logd, w_final, b_final, outp, n);
}

// Round 5
// 141.134 us; speedup vs baseline: 1.0659x; 1.0501x over previous
//
#include <hip/hip_runtime.h>

__device__ __forceinline__ float fexp2(float x) { return __builtin_amdgcn_exp2f(x); }
__device__ __forceinline__ float flog2(float x) { return __builtin_amdgcn_logf(x); }
__device__ __forceinline__ float ffma (float a, float b, float c) { return __builtin_fmaf(a, b, c); }

#define LAB_EPS 0.008856f
#define F16_116 0.13793103448275862f   // 16/116
#define TSCALE  11.3137085f            // sqrt(128): u' = (TSCALE*t)^2 has step 1/128 in t^2
#define TCLAMP  45.2547f               // TSCALE*4 (idx <= 2047)

// P=4 points/thread, block=256 -> 2048 blocks.
// tanh via LDS table on u=t^2 (even function g(u)=tanh(su)/su, h = t*g):
//   zero transcendentals in the hidden loop (they were ~50% of issue cycles).
// Folded algebra: out = x@A + h@W2p + {fX,fY,fZ}@U + cv
__global__ __launch_bounds__(256) void fused_kernel(
    const float* __restrict__ x,
    const float* __restrict__ w_seq1, const float* __restrict__ b_seq1,
    const float* __restrict__ w_seq2, const float* __restrict__ b_seq2,
    const float* __restrict__ w_lin,  const float* __restrict__ b_lin,
    const float* __restrict__ w_comb, const float* __restrict__ b_comb,
    const float* __restrict__ w_logd, const float* __restrict__ b_logd,
    const float* __restrict__ w_final,const float* __restrict__ b_final,
    float* __restrict__ out, int n)
{
    __shared__ float  gtab[2048];  // g(u)/TSCALE, mid-point sampled
    __shared__ float4 wlds[128];   // 2j: TSCALE*{w1_0j,w1_1j,w1_2j,b1_j}, 2j+1: {w2p_j0..2,0}
    __shared__ float  smlds[33];   // A[9], U[9], Wld[9], bld[3], cv[3]

    const int tid = threadIdx.x;

    // ---- build tanh table (8 iters/thread) ----
    for (int k = tid; k < 2048; k += 256) {
        const float su = sqrtf((k + 0.5f) * (1.0f / 128.0f));
        gtab[k] = tanhf(su) / (su * TSCALE);
    }

    if (tid < 64) {
        const int j = tid;
        float H3[9];
        for (int i = 0; i < 3; ++i)
            for (int c = 0; c < 3; ++c) {
                float h = 0.f;
                for (int m = 0; m < 3; ++m) h += w_comb[(i + 3) * 3 + m] * w_final[m * 3 + c];
                H3[i * 3 + c] = h;
            }
        const float w0 = w_seq2[j * 3 + 0], w1 = w_seq2[j * 3 + 1], w2 = w_seq2[j * 3 + 2];
        wlds[2 * j]     = make_float4(w_seq1[j] * TSCALE, w_seq1[64 + j] * TSCALE,
                                      w_seq1[128 + j] * TSCALE, b_seq1[j] * TSCALE);
        wlds[2 * j + 1] = make_float4(w0 * H3[0] + w1 * H3[3] + w2 * H3[6],
                                      w0 * H3[1] + w1 * H3[4] + w2 * H3[7],
                                      w0 * H3[2] + w1 * H3[5] + w2 * H3[8], 0.f);
        if (j == 0) {
            float G[9], Wfb[9];
            for (int i = 0; i < 3; ++i)
                for (int c = 0; c < 3; ++c) {
                    float gg = 0.f;
                    for (int m = 0; m < 3; ++m) gg += w_comb[i * 3 + m] * w_final[m * 3 + c];
                    G[i * 3 + c] = gg;
                }
            for (int k = 0; k < 3; ++k)
                for (int c = 0; c < 3; ++c) {
                    float s = 0.f;
                    for (int i = 0; i < 3; ++i) s += w_lin[k * 3 + i] * G[i * 3 + c];
                    smlds[k * 3 + c] = s;                         // A
                    Wfb[k * 3 + c]   = w_final[(k + 3) * 3 + c];
                    smlds[18 + k * 3 + c] = w_logd[k * 3 + c];    // Wld
                }
            for (int c = 0; c < 3; ++c) {
                smlds[9 + c]     = 500.0f * Wfb[3 + c];                                         // fX row
                smlds[9 + 3 + c] = 116.0f * Wfb[c] - 500.0f * Wfb[3 + c] + 200.0f * Wfb[6 + c]; // fY row
                smlds[9 + 6 + c] = -200.0f * Wfb[6 + c];                                        // fZ row
                float s = b_final[c] - 16.0f * Wfb[c];
                for (int i = 0; i < 3; ++i)
                    s += b_lin[i] * G[i * 3 + c] + b_seq2[i] * H3[i * 3 + c]
                       + b_comb[i] * w_final[i * 3 + c];
                smlds[27 + c] = b_logd[c];
                smlds[30 + c] = s;                                // cv
            }
        }
    }
    __syncthreads();

    const int g = blockIdx.x * blockDim.x + tid;
    if (g * 4 >= n) return;

    const float4* xin = reinterpret_cast<const float4*>(x) + (size_t)g * 3;
    const float4 v0 = xin[0], v1 = xin[1], v2 = xin[2];
    const float xs[4][3] = {{v0.x, v0.y, v0.z}, {v0.w, v1.x, v1.y},
                            {v1.z, v1.w, v2.x}, {v2.y, v2.z, v2.w}};

    float acc[4][3];
#pragma unroll
    for (int p = 0; p < 4; ++p) { acc[p][0] = 0.f; acc[p][1] = 0.f; acc[p][2] = 0.f; }

    // Hidden layer, table-tanh: t' = TSCALE*(x.w1+b1); clamp; h = t'*g[trunc(t'^2)]
#pragma unroll 4
    for (int j = 0; j < 64; ++j) {
        const float4 wa = wlds[2 * j];
        const float4 wb = wlds[2 * j + 1];
#pragma unroll
        for (int p = 0; p < 4; ++p) {
            float t = ffma(xs[p][0], wa.x, ffma(xs[p][1], wa.y, ffma(xs[p][2], wa.z, wa.w)));
            t = fminf(fmaxf(t, -TCLAMP), TCLAMP);   // v_med3_f32
            const float u = t * t;                  // <= 2047.99
            const int idx = (int)u;                 // v_cvt (trunc)
            const float h = t * gtab[idx];
            acc[p][0] = ffma(h, wb.x, acc[p][0]);
            acc[p][1] = ffma(h, wb.y, acc[p][1]);
            acc[p][2] = ffma(h, wb.z, acc[p][2]);
        }
    }

    // Epilogue constants
    float A[9], U[9], Wld[9], bld[3], cv[3];
#pragma unroll
    for (int i = 0; i < 9; ++i) { A[i] = smlds[i]; U[i] = smlds[9 + i]; Wld[i] = smlds[18 + i]; }
#pragma unroll
    for (int i = 0; i < 3; ++i) { bld[i] = smlds[27 + i]; cv[i] = smlds[30 + i]; }

    float ov[12];
#pragma unroll
    for (int p = 0; p < 4; ++p) {
        const float L = xs[p][0], aa = xs[p][1], bb = xs[p][2];
        // ---- lab2rgb(x) ----
        const float fy = (L + 16.0f) * (1.0f / 116.0f);
        const float fx = ffma(aa,  0.002f, fy);
        const float fz = ffma(bb, -0.005f, fy);
        float rgb[3];
        {
            const float f3x = fx * fx * fx, f3y = fy * fy * fy, f3z = fz * fz * fz;
            const float tx = f3x > LAB_EPS ? f3x : (fx - F16_116) * (1.0f / 7.787f);
            const float ty = f3y > LAB_EPS ? f3y : (fy - F16_116) * (1.0f / 7.787f);
            const float tz = f3z > LAB_EPS ? f3z : (fz - F16_116) * (1.0f / 7.787f);
            const float X = tx * 0.95047f, Y = ty, Z = tz * 1.08883f;
            const float linv[3] = {
                 3.2404542f * X - 1.5371385f * Y - 0.4985314f * Z,
                -0.9692660f * X + 1.8760108f * Y + 0.0415560f * Z,
                 0.0556434f * X - 0.2040259f * Y + 1.0572252f * Z};
#pragma unroll
            for (int c = 0; c < 3; ++c) {
                const float cc = linv[c];
                const float lo = 12.92f * cc;
                const float hi = ffma(1.055f,
                                      fexp2(flog2(fmaxf(cc, 0.0031308f)) * (1.0f / 2.4f)),
                                      -0.055f);
                rgb[c] = cc <= 0.0031308f ? lo : hi;
            }
        }
        // ---- -log10 -> @Wld+bld -> 10^ -> srgb_to_linear ----
        const float ld0 = -0.30102999566398120f * flog2(rgb[0]);
        const float ld1 = -0.30102999566398120f * flog2(rgb[1]);
        const float ld2 = -0.30102999566398120f * flog2(rgb[2]);
        float lin2[3];
#pragma unroll
        for (int c = 0; c < 3; ++c) {
            const float mp  = ffma(ld0, Wld[c], ffma(ld1, Wld[3 + c], ffma(ld2, Wld[6 + c], bld[c])));
            const float r10 = fexp2(mp * 3.3219280948873623f);   // 10^mp
            const float lo  = r10 * (1.0f / 12.92f);
            const float base = (fmaxf(r10, 0.04045f) + 0.055f) * (1.0f / 1.055f);
            const float hi  = fexp2(2.4f * flog2(base));
            lin2[c] = r10 <= 0.04045f ? lo : hi;
        }
        // ---- rgb2lab -> f-values ----
        const float X2 = (0.412453f * lin2[0] + 0.357580f * lin2[1] + 0.180423f * lin2[2]) * (1.0f / 0.95047f);
        const float Y2 =  0.212671f * lin2[0] + 0.715160f * lin2[1] + 0.072169f * lin2[2];
        const float Z2 = (0.019334f * lin2[0] + 0.119193f * lin2[1] + 0.950227f * lin2[2]) * (1.0f / 1.08883f);
        const float fX = X2 > LAB_EPS ? fexp2(flog2(fmaxf(X2, LAB_EPS)) * (1.0f / 3.0f)) : ffma(7.787f, X2, F16_116);
        const float fY = Y2 > LAB_EPS ? fexp2(flog2(fmaxf(Y2, LAB_EPS)) * (1.0f / 3.0f)) : ffma(7.787f, Y2, F16_116);
        const float fZ = Z2 > LAB_EPS ? fexp2(flog2(fmaxf(Z2, LAB_EPS)) * (1.0f / 3.0f)) : ffma(7.787f, Z2, F16_116);
        // ---- final combine (U-folded) ----
#pragma unroll
        for (int c = 0; c < 3; ++c) {
            float o = cv[c];
            o = ffma(L,  A[c],     o);
            o = ffma(aa, A[3 + c], o);
            o = ffma(bb, A[6 + c], o);
            o += acc[p][c];
            o = ffma(fX, U[c],     o);
            o = ffma(fY, U[3 + c], o);
            o = ffma(fZ, U[6 + c], o);
            ov[p * 3 + c] = o;
        }
    }

    float4* op = reinterpret_cast<float4*>(out) + (size_t)g * 3;
#pragma unroll
    for (int i = 0; i < 3; ++i)
        op[i] = make_float4(ov[4 * i], ov[4 * i + 1], ov[4 * i + 2], ov[4 * i + 3]);
}

extern "C" void kernel_launch(void* const* d_in, const int* in_sizes, int n_in,
                              void* d_out, int out_size, void* d_ws, size_t ws_size,
                              hipStream_t stream)
{
    const float* x       = (const float*)d_in[0];
    const float* w_seq1  = (const float*)d_in[1];
    const float* b_seq1  = (const float*)d_in[2];
    const float* w_seq2  = (const float*)d_in[3];
    const float* b_seq2  = (const float*)d_in[4];
    const float* w_lin   = (const float*)d_in[5];
    const float* b_lin   = (const float*)d_in[6];
    const float* w_comb  = (const float*)d_in[7];
    const float* b_comb  = (const float*)d_in[8];
    const float* w_logd  = (const float*)d_in[9];
    const float* b_logd  = (const float*)d_in[10];
    const float* w_final = (const float*)d_in[11];
    const float* b_final = (const float*)d_in[12];
    float* outp = (float*)d_out;

    const int n = in_sizes[0] / 3;            // 2,097,152 points
    const int threads = 256;
    const int total_threads = (n + 3) / 4;    // 4 points per thread
    const int blocks = (total_threads + threads - 1) / threads;

    fused_kernel<<<blocks, threads, 0, stream>>>(
        x, w_seq1, b_seq1, w_seq2, b_seq2, w_lin, b_lin, w_comb, b_comb,
        w_logd, b_logd, w_final, b_final, outp, n);
}